// Round 8
// baseline (632.188 us; speedup 1.0000x reference)
//
#include <hip/hip_runtime.h>
#include <hip/hip_fp16.h>
#include <math.h>

#define K1 128     // input feature dim
#define C  64      // hidden == output channels
#define SCAN_B 1024
#define NPART 8    // dst-range partitions == XCD count (bid%8 round-robin)

// ---- edge dtype detection: int64 edges have all-zero high words ----
__global__ void detect_kernel(const int* __restrict__ e, int twoE, int* __restrict__ flag) {
    __shared__ int nz;
    if (threadIdx.x == 0) nz = 0;
    __syncthreads();
    int nchk = twoE / 2; if (nchk > 4096) nchk = 4096;
    int bad = 0;
    for (int i = threadIdx.x; i < nchk; i += blockDim.x)
        if (e[2 * i + 1] != 0) bad = 1;
    if (bad) atomicOr(&nz, 1);
    __syncthreads();
    if (threadIdx.x == 0) *flag = nz ? 0 : 1;   // 1 => int64
}

__device__ __forceinline__ int load_dst(const void* EI, int E, int e, int is64) {
    return is64 ? (int)((const long long*)EI)[(size_t)E + e] : ((const int*)EI)[(size_t)E + e];
}
__device__ __forceinline__ int load_src(const void* EI, int E, int e, int is64) {
    return is64 ? (int)((const long long*)EI)[e] : ((const int*)EI)[e];
}

// ---- per-node in-degree histogram, dst-range partitioned per XCD ----
__global__ __launch_bounds__(256) void hist_kernel(const void* __restrict__ EI, int E,
        const int* __restrict__ flag, int* __restrict__ cnt, int n) {
    const int is64 = *flag;
    const int part = blockIdx.x & (NPART - 1);
    const int span = (n + NPART - 1) / NPART;
    const int lo = part * span;
    const int hi = (lo + span < n) ? lo + span : n;
    const int blk = blockIdx.x >> 3, nblk = gridDim.x >> 3;
    for (int e = blk * 256 + threadIdx.x; e < E; e += nblk * 256) {
        int d = load_dst(EI, E, e, is64);
        if (d >= lo && d < hi) atomicAdd(&cnt[d], 1);
    }
}

// ---- exclusive scan of cnt -> rowptr (3 phases); dinv fused into phase 1 ----
__global__ __launch_bounds__(SCAN_B) void scan1_kernel(const int* __restrict__ cnt, int n,
        int* __restrict__ ex, int* __restrict__ bsum, float* __restrict__ dinv) {
    __shared__ int s[SCAN_B];
    int i = blockIdx.x * SCAN_B + threadIdx.x;
    int v = (i < n) ? cnt[i] : 0;
    s[threadIdx.x] = v;
    __syncthreads();
    for (int off = 1; off < SCAN_B; off <<= 1) {
        int t = (threadIdx.x >= off) ? s[threadIdx.x - off] : 0;
        __syncthreads();
        s[threadIdx.x] += t;
        __syncthreads();
    }
    if (i < n) {
        ex[i] = s[threadIdx.x] - v;               // exclusive within block
        dinv[i] = rsqrtf((float)(v + 1));         // +1 self-loop
    }
    if (threadIdx.x == SCAN_B - 1) bsum[blockIdx.x] = s[SCAN_B - 1];
}

__global__ void scan2_kernel(int* __restrict__ bsum, int nb) {
    const int lane = threadIdx.x & 63;
    int acc = 0;
    for (int base = 0; base < nb; base += 64) {
        int v = (base + lane < nb) ? bsum[base + lane] : 0;
        int sc = v;
        #pragma unroll
        for (int off = 1; off < 64; off <<= 1) {
            int t = __shfl_up(sc, off, 64);
            if (lane >= off) sc += t;
        }
        if (base + lane < nb) bsum[base + lane] = acc + sc - v;   // exclusive
        acc += __shfl(sc, 63, 64);
    }
}

__global__ void scan3_kernel(int* __restrict__ ex, const int* __restrict__ bsum,
                             int* __restrict__ fill, int n, int Etot) {
    for (int i = blockIdx.x * blockDim.x + threadIdx.x; i < n; i += gridDim.x * blockDim.x) {
        int v = ex[i] + bsum[i / SCAN_B];
        ex[i] = v;
        fill[i] = v;
    }
    if (blockIdx.x == 0 && threadIdx.x == 0) ex[n] = Etot;
}

// ---- scatter into CSR order, dst-range partitioned per XCD ----
__global__ __launch_bounds__(256) void scatter_kernel(const void* __restrict__ EI, int E,
        const int* __restrict__ flag, int* __restrict__ fill, int* __restrict__ csr,
        int n) {
    const int is64 = *flag;
    const int part = blockIdx.x & (NPART - 1);
    const int span = (n + NPART - 1) / NPART;
    const int lo = part * span;
    const int hi = (lo + span < n) ? lo + span : n;
    const int blk = blockIdx.x >> 3, nblk = gridDim.x >> 3;
    for (int e = blk * 256 + threadIdx.x; e < E; e += nblk * 256) {
        int d = load_dst(EI, E, e, is64);
        if (d >= lo && d < hi) {
            int s = load_src(EI, E, e, is64);
            int pos = atomicAdd(&fill[d], 1);
            csr[pos] = s;
        }
    }
}

// ---- fast GEMM: G = f16((X @ W) * dinv). Tile of 64 rows staged in LDS via
// coalesced float4; lane's W column held in VGPRs (compile-time indexed);
// compute reads Xs via uniform-address float4 broadcast (bank-conflict-free).
template<int K>
__global__ __launch_bounds__(256) void gemmf_kernel(const float* __restrict__ X,
        const float* __restrict__ W, const float* __restrict__ dinv,
        __half* __restrict__ G, int n, int ntiles)
{
    __shared__ __align__(16) float Xs[64 * K];
    const int lane = threadIdx.x & 63;
    const int wv = threadIdx.x >> 6;
    float w[K];
    #pragma unroll
    for (int k = 0; k < K; ++k) w[k] = W[k * C + lane];   // coalesced, hoisted
    for (int tile = blockIdx.x; tile < ntiles; tile += gridDim.x) {
        const int base = tile * 64;
        int rows = n - base; if (rows > 64) rows = 64;
        __syncthreads();   // protect Xs from previous iteration's readers
        for (int i = threadIdx.x; i < rows * (K / 4); i += 256) {
            const int r = i / (K / 4), c4 = i % (K / 4);
            ((float4*)(Xs + r * K))[c4] = ((const float4*)(X + (size_t)(base + r) * K))[c4];
        }
        __syncthreads();
        const int r0 = wv * 16;
        int r1 = r0 + 16; if (r1 > rows) r1 = rows;
        for (int r = r0; r < r1; ++r) {
            float acc = 0.f;
            #pragma unroll
            for (int k4 = 0; k4 < K / 4; ++k4) {
                float4 x4 = ((const float4*)(Xs + r * K))[k4];   // broadcast read
                acc = fmaf(x4.x, w[4 * k4 + 0], acc);
                acc = fmaf(x4.y, w[4 * k4 + 1], acc);
                acc = fmaf(x4.z, w[4 * k4 + 2], acc);
                acc = fmaf(x4.w, w[4 * k4 + 3], acc);
            }
            G[(size_t)(base + r) * C + lane] = __float2half_rn(acc * dinv[base + r]);
        }
    }
}

// ---- pure CSR gather (f16 G, f32 accum), one wave per dst row ----
// 8-deep MLP for ALL edges: tail handled by wave-uniform guards (no divergence).
// MODE 0 = relu + b1 -> f32 Out ; MODE 1 = b2 + log_softmax -> f32 Out
template<int MODE>
__global__ __launch_bounds__(256) void gather_kernel(const int* __restrict__ rowptr,
        const int* __restrict__ csr, const __half* __restrict__ G,
        const float* __restrict__ dinv, const float* __restrict__ bias,
        float* __restrict__ Out, int n)
{
    const int lane = threadIdx.x & 63;
    const int v = __builtin_amdgcn_readfirstlane((int)(blockIdx.x * 4 + (threadIdx.x >> 6)));
    if (v >= n) return;
    const int start = __builtin_amdgcn_readfirstlane(rowptr[v]);
    const int end   = __builtin_amdgcn_readfirstlane(rowptr[v + 1]);
    float a[8];
    a[0] = __half2float(G[(size_t)v * C + lane]);   // self-loop term
    #pragma unroll
    for (int t = 1; t < 8; ++t) a[t] = 0.f;
    for (int base = start; base < end; base += 64) {
        int m = end - base; if (m > 64) m = 64;
        int idx = (lane < m) ? csr[base + lane] : 0;
        for (int j = 0; j < m; j += 8) {
            #pragma unroll
            for (int t = 0; t < 8; ++t) {
                if (j + t < m) {                     // wave-uniform guard
                    int s = __shfl(idx, j + t, 64);
                    a[t] += __half2float(G[(size_t)s * C + lane]);
                }
            }
        }
    }
    float acc = ((a[0] + a[1]) + (a[2] + a[3])) + ((a[4] + a[5]) + (a[6] + a[7]));
    float y = fmaf(acc, dinv[v], bias[lane]);
    if (MODE == 0) {
        Out[(size_t)v * C + lane] = y > 0.f ? y : 0.f;
    } else {
        float mx = y;
        #pragma unroll
        for (int off = 32; off > 0; off >>= 1) mx = fmaxf(mx, __shfl_xor(mx, off, 64));
        float ex = expf(y - mx);
        float l = ex;
        #pragma unroll
        for (int off = 32; off > 0; off >>= 1) l += __shfl_xor(l, off, 64);
        Out[(size_t)v * C + lane] = y - mx - logf(l);
    }
}

static inline size_t align16(size_t x) { return (x + 15) & ~(size_t)15; }

extern "C" void kernel_launch(void* const* d_in, const int* in_sizes, int n_in,
                              void* d_out, int out_size, void* d_ws, size_t ws_size,
                              hipStream_t stream)
{
    const float* X  = (const float*)d_in[0];
    const void*  EI = d_in[1];
    const float* W1 = (const float*)d_in[3];
    const float* b1 = (const float*)d_in[4];
    const float* W2 = (const float*)d_in[5];
    const float* b2 = (const float*)d_in[6];
    float* Out = (float*)d_out;

    const int n    = in_sizes[0] / K1;
    const int E    = in_sizes[1] / 2;
    const int twoE = 2 * E;
    const int nb   = (n + SCAN_B - 1) / SCAN_B;
    const int ntiles = (n + 63) / 64;

    // workspace layout (~34 MB)
    char* ws = (char*)d_ws;
    size_t off = 0;
    int*    csr    = (int*)(ws + off);    off = align16(off + (size_t)E * 4);
    int*    rowptr = (int*)(ws + off);    off = align16(off + (size_t)(n + 1) * 4);
    int*    cnt    = (int*)(ws + off);    off = align16(off + (size_t)n * 4);
    int*    bsum   = (int*)(ws + off);    off = align16(off + (size_t)(nb + 1) * 4);
    int*    flag   = (int*)(ws + off);    off = align16(off + 16);
    float*  dinv   = (float*)(ws + off);  off = align16(off + (size_t)n * 4);
    __half* G      = (__half*)(ws + off); off = align16(off + (size_t)n * C * 2);
    __half* G2     = (__half*)(ws + off); off = align16(off + (size_t)n * C * 2);
    int*    fill   = cnt;                 // cnt dead after scan1
    float*  H      = Out;                 // layer-1 activations staged in d_out (f32)

    hipLaunchKernelGGL(detect_kernel, dim3(1), dim3(256), 0, stream, (const int*)EI, twoE, flag);
    hipMemsetAsync(cnt, 0, (size_t)n * 4, stream);

    // CSR build (hist & scatter dst-partitioned, XCD-local via bid%8)
    hipLaunchKernelGGL(hist_kernel,  dim3(2048), dim3(256), 0, stream, EI, E, flag, cnt, n);
    hipLaunchKernelGGL(scan1_kernel, dim3(nb), dim3(SCAN_B), 0, stream, cnt, n, rowptr, bsum, dinv);
    hipLaunchKernelGGL(scan2_kernel, dim3(1), dim3(64), 0, stream, bsum, nb);
    hipLaunchKernelGGL(scan3_kernel, dim3(1024), dim3(256), 0, stream, rowptr, bsum, fill, n, E);
    hipLaunchKernelGGL(scatter_kernel, dim3(2048), dim3(256), 0, stream, EI, E, flag, fill, csr, n);

    const int ngb = (n + 3) / 4;   // one wave per row for gathers

    // layer 1: G = f16((X@W1)*dinv) ; H = relu(gather(G)*dinv + b1)  (H in d_out)
    hipLaunchKernelGGL((gemmf_kernel<K1>), dim3(ntiles), dim3(256), 0, stream, X, W1, dinv, G, n, ntiles);
    hipLaunchKernelGGL((gather_kernel<0>), dim3(ngb), dim3(256), 0, stream, rowptr, csr, G, dinv, b1, H, n);

    // layer 2: G2 = f16((H@W2)*dinv) ; Out = log_softmax(gather(G2)*dinv + b2)
    hipLaunchKernelGGL((gemmf_kernel<C>), dim3(ntiles), dim3(256), 0, stream, H, W2, dinv, G2, n, ntiles);
    hipLaunchKernelGGL((gather_kernel<1>), dim3(ngb), dim3(256), 0, stream, rowptr, csr, G2, dinv, b2, Out, n);
}

// Round 9
// 619.435 us; speedup vs baseline: 1.0206x; 1.0206x over previous
//
#include <hip/hip_runtime.h>
#include <hip/hip_fp16.h>
#include <math.h>

#define K1 128     // input feature dim
#define C  64      // hidden == output channels
#define SCAN_B 1024
#define NPART 8    // dst-range partitions == XCD count (bid%8 round-robin)

// ---- edge dtype detection: int64 edges have all-zero high words ----
__global__ void detect_kernel(const int* __restrict__ e, int twoE, int* __restrict__ flag) {
    __shared__ int nz;
    if (threadIdx.x == 0) nz = 0;
    __syncthreads();
    int nchk = twoE / 2; if (nchk > 4096) nchk = 4096;
    int bad = 0;
    for (int i = threadIdx.x; i < nchk; i += blockDim.x)
        if (e[2 * i + 1] != 0) bad = 1;
    if (bad) atomicOr(&nz, 1);
    __syncthreads();
    if (threadIdx.x == 0) *flag = nz ? 0 : 1;   // 1 => int64
}

__device__ __forceinline__ int load_dst(const void* EI, int E, int e, int is64) {
    return is64 ? (int)((const long long*)EI)[(size_t)E + e] : ((const int*)EI)[(size_t)E + e];
}
__device__ __forceinline__ int load_src(const void* EI, int E, int e, int is64) {
    return is64 ? (int)((const long long*)EI)[e] : ((const int*)EI)[e];
}

// ---- per-node in-degree histogram, dst-range partitioned per XCD ----
__global__ __launch_bounds__(256) void hist_kernel(const void* __restrict__ EI, int E,
        const int* __restrict__ flag, int* __restrict__ cnt, int n) {
    const int is64 = *flag;
    const int part = blockIdx.x & (NPART - 1);
    const int span = (n + NPART - 1) / NPART;
    const int lo = part * span;
    const int hi = (lo + span < n) ? lo + span : n;
    const int blk = blockIdx.x >> 3, nblk = gridDim.x >> 3;
    for (int e = blk * 256 + threadIdx.x; e < E; e += nblk * 256) {
        int d = load_dst(EI, E, e, is64);
        if (d >= lo && d < hi) atomicAdd(&cnt[d], 1);
    }
}

// ---- exclusive scan of cnt -> rowptr (3 phases); dinv fused into phase 1 ----
__global__ __launch_bounds__(SCAN_B) void scan1_kernel(const int* __restrict__ cnt, int n,
        int* __restrict__ ex, int* __restrict__ bsum, float* __restrict__ dinv) {
    __shared__ int s[SCAN_B];
    int i = blockIdx.x * SCAN_B + threadIdx.x;
    int v = (i < n) ? cnt[i] : 0;
    s[threadIdx.x] = v;
    __syncthreads();
    for (int off = 1; off < SCAN_B; off <<= 1) {
        int t = (threadIdx.x >= off) ? s[threadIdx.x - off] : 0;
        __syncthreads();
        s[threadIdx.x] += t;
        __syncthreads();
    }
    if (i < n) {
        ex[i] = s[threadIdx.x] - v;               // exclusive within block
        dinv[i] = rsqrtf((float)(v + 1));         // +1 self-loop
    }
    if (threadIdx.x == SCAN_B - 1) bsum[blockIdx.x] = s[SCAN_B - 1];
}

__global__ void scan2_kernel(int* __restrict__ bsum, int nb) {
    const int lane = threadIdx.x & 63;
    int acc = 0;
    for (int base = 0; base < nb; base += 64) {
        int v = (base + lane < nb) ? bsum[base + lane] : 0;
        int sc = v;
        #pragma unroll
        for (int off = 1; off < 64; off <<= 1) {
            int t = __shfl_up(sc, off, 64);
            if (lane >= off) sc += t;
        }
        if (base + lane < nb) bsum[base + lane] = acc + sc - v;   // exclusive
        acc += __shfl(sc, 63, 64);
    }
}

__global__ void scan3_kernel(int* __restrict__ ex, const int* __restrict__ bsum,
                             int* __restrict__ fill, int n, int Etot) {
    for (int i = blockIdx.x * blockDim.x + threadIdx.x; i < n; i += gridDim.x * blockDim.x) {
        int v = ex[i] + bsum[i / SCAN_B];
        ex[i] = v;
        fill[i] = v;
    }
    if (blockIdx.x == 0 && threadIdx.x == 0) ex[n] = Etot;
}

// ---- scatter into CSR order, dst-range partitioned per XCD ----
__global__ __launch_bounds__(256) void scatter_kernel(const void* __restrict__ EI, int E,
        const int* __restrict__ flag, int* __restrict__ fill, int* __restrict__ csr,
        int n) {
    const int is64 = *flag;
    const int part = blockIdx.x & (NPART - 1);
    const int span = (n + NPART - 1) / NPART;
    const int lo = part * span;
    const int hi = (lo + span < n) ? lo + span : n;
    const int blk = blockIdx.x >> 3, nblk = gridDim.x >> 3;
    for (int e = blk * 256 + threadIdx.x; e < E; e += nblk * 256) {
        int d = load_dst(EI, E, e, is64);
        if (d >= lo && d < hi) {
            int s = load_src(EI, E, e, is64);
            int pos = atomicAdd(&fill[d], 1);
            csr[pos] = s;
        }
    }
}

// ---- GEMM: G = f16((X @ W) * dinv). Occupancy-first design:
// W in LDS k-major (Ws[k*64+lane] reads are 2-way bank alias = free).
// Each wave: 8 rows, k4-blocked. Per k4: 8 wave-uniform float4 X loads +
// 4 LDS b32 + 32 FMAs in 8 independent chains. ~70 VGPR -> 4+ waves/SIMD.
template<int K>
__global__ __launch_bounds__(256) void gemmf_kernel(const float* __restrict__ X,
        const float* __restrict__ W, const float* __restrict__ dinv,
        __half* __restrict__ G, int n)
{
    __shared__ float Ws[K * C];
    for (int i = threadIdx.x; i < K * C; i += 256) Ws[i] = W[i];
    __syncthreads();
    const int lane = threadIdx.x & 63;
    const int wv = threadIdx.x >> 6;
    const int R = 8;
    for (int base0 = blockIdx.x * (4 * R); base0 < n; base0 += gridDim.x * (4 * R)) {
        const int base = base0 + wv * R;
        if (base >= n) continue;
        const int rows = (base + R <= n) ? R : (n - base);
        float acc[R];
        #pragma unroll
        for (int r = 0; r < R; ++r) acc[r] = 0.f;
        if (rows == R) {
            for (int k4 = 0; k4 < K / 4; ++k4) {
                float4 xv[R];
                #pragma unroll
                for (int r = 0; r < R; ++r)
                    xv[r] = *(const float4*)(X + (size_t)(base + r) * K + 4 * k4);
                const float w0 = Ws[(4 * k4 + 0) * C + lane];
                const float w1 = Ws[(4 * k4 + 1) * C + lane];
                const float w2 = Ws[(4 * k4 + 2) * C + lane];
                const float w3 = Ws[(4 * k4 + 3) * C + lane];
                #pragma unroll
                for (int r = 0; r < R; ++r) {
                    acc[r] = fmaf(xv[r].x, w0, acc[r]);
                    acc[r] = fmaf(xv[r].y, w1, acc[r]);
                    acc[r] = fmaf(xv[r].z, w2, acc[r]);
                    acc[r] = fmaf(xv[r].w, w3, acc[r]);
                }
            }
            #pragma unroll
            for (int r = 0; r < R; ++r)
                G[(size_t)(base + r) * C + lane] = __float2half_rn(acc[r] * dinv[base + r]);
        } else {
            for (int r = 0; r < rows; ++r) {
                float a = 0.f;
                for (int k = 0; k < K; ++k)
                    a = fmaf(X[(size_t)(base + r) * K + k], Ws[k * C + lane], a);
                G[(size_t)(base + r) * C + lane] = __float2half_rn(a * dinv[base + r]);
            }
        }
    }
}

// ---- pure CSR gather (f16 G, f32 accum), one wave per dst row ----
// 8-deep MLP for ALL edges: tail handled by wave-uniform guards (no divergence).
// MODE 0 = relu + b1 -> f32 Out ; MODE 1 = b2 + log_softmax -> f32 Out
template<int MODE>
__global__ __launch_bounds__(256) void gather_kernel(const int* __restrict__ rowptr,
        const int* __restrict__ csr, const __half* __restrict__ G,
        const float* __restrict__ dinv, const float* __restrict__ bias,
        float* __restrict__ Out, int n)
{
    const int lane = threadIdx.x & 63;
    const int v = __builtin_amdgcn_readfirstlane((int)(blockIdx.x * 4 + (threadIdx.x >> 6)));
    if (v >= n) return;
    const int start = __builtin_amdgcn_readfirstlane(rowptr[v]);
    const int end   = __builtin_amdgcn_readfirstlane(rowptr[v + 1]);
    float a[8];
    a[0] = __half2float(G[(size_t)v * C + lane]);   // self-loop term
    #pragma unroll
    for (int t = 1; t < 8; ++t) a[t] = 0.f;
    for (int base = start; base < end; base += 64) {
        int m = end - base; if (m > 64) m = 64;
        int idx = (lane < m) ? csr[base + lane] : 0;
        for (int j = 0; j < m; j += 8) {
            #pragma unroll
            for (int t = 0; t < 8; ++t) {
                if (j + t < m) {                     // wave-uniform guard
                    int s = __shfl(idx, j + t, 64);
                    a[t] += __half2float(G[(size_t)s * C + lane]);
                }
            }
        }
    }
    float acc = ((a[0] + a[1]) + (a[2] + a[3])) + ((a[4] + a[5]) + (a[6] + a[7]));
    float y = fmaf(acc, dinv[v], bias[lane]);
    if (MODE == 0) {
        Out[(size_t)v * C + lane] = y > 0.f ? y : 0.f;
    } else {
        float mx = y;
        #pragma unroll
        for (int off = 32; off > 0; off >>= 1) mx = fmaxf(mx, __shfl_xor(mx, off, 64));
        float ex = expf(y - mx);
        float l = ex;
        #pragma unroll
        for (int off = 32; off > 0; off >>= 1) l += __shfl_xor(l, off, 64);
        Out[(size_t)v * C + lane] = y - mx - logf(l);
    }
}

static inline size_t align16(size_t x) { return (x + 15) & ~(size_t)15; }

extern "C" void kernel_launch(void* const* d_in, const int* in_sizes, int n_in,
                              void* d_out, int out_size, void* d_ws, size_t ws_size,
                              hipStream_t stream)
{
    const float* X  = (const float*)d_in[0];
    const void*  EI = d_in[1];
    const float* W1 = (const float*)d_in[3];
    const float* b1 = (const float*)d_in[4];
    const float* W2 = (const float*)d_in[5];
    const float* b2 = (const float*)d_in[6];
    float* Out = (float*)d_out;

    const int n    = in_sizes[0] / K1;
    const int E    = in_sizes[1] / 2;
    const int twoE = 2 * E;
    const int nb   = (n + SCAN_B - 1) / SCAN_B;

    // workspace layout (~34 MB)
    char* ws = (char*)d_ws;
    size_t off = 0;
    int*    csr    = (int*)(ws + off);    off = align16(off + (size_t)E * 4);
    int*    rowptr = (int*)(ws + off);    off = align16(off + (size_t)(n + 1) * 4);
    int*    cnt    = (int*)(ws + off);    off = align16(off + (size_t)n * 4);
    int*    bsum   = (int*)(ws + off);    off = align16(off + (size_t)(nb + 1) * 4);
    int*    flag   = (int*)(ws + off);    off = align16(off + 16);
    float*  dinv   = (float*)(ws + off);  off = align16(off + (size_t)n * 4);
    __half* G      = (__half*)(ws + off); off = align16(off + (size_t)n * C * 2);
    __half* G2     = (__half*)(ws + off); off = align16(off + (size_t)n * C * 2);
    int*    fill   = cnt;                 // cnt dead after scan1
    float*  H      = Out;                 // layer-1 activations staged in d_out (f32)

    hipLaunchKernelGGL(detect_kernel, dim3(1), dim3(256), 0, stream, (const int*)EI, twoE, flag);
    hipMemsetAsync(cnt, 0, (size_t)n * 4, stream);

    // CSR build (hist & scatter dst-partitioned, XCD-local via bid%8)
    hipLaunchKernelGGL(hist_kernel,  dim3(2048), dim3(256), 0, stream, EI, E, flag, cnt, n);
    hipLaunchKernelGGL(scan1_kernel, dim3(nb), dim3(SCAN_B), 0, stream, cnt, n, rowptr, bsum, dinv);
    hipLaunchKernelGGL(scan2_kernel, dim3(1), dim3(64), 0, stream, bsum, nb);
    hipLaunchKernelGGL(scan3_kernel, dim3(1024), dim3(256), 0, stream, rowptr, bsum, fill, n, E);
    hipLaunchKernelGGL(scatter_kernel, dim3(2048), dim3(256), 0, stream, EI, E, flag, fill, csr, n);

    const int ngb = (n + 3) / 4;   // one wave per row for gathers

    // layer 1: G = f16((X@W1)*dinv) ; H = relu(gather(G)*dinv + b1)  (H in d_out)
    hipLaunchKernelGGL((gemmf_kernel<K1>), dim3(2048), dim3(256), 0, stream, X, W1, dinv, G, n);
    hipLaunchKernelGGL((gather_kernel<0>), dim3(ngb), dim3(256), 0, stream, rowptr, csr, G, dinv, b1, H, n);

    // layer 2: G2 = f16((H@W2)*dinv) ; Out = log_softmax(gather(G2)*dinv + b2)
    hipLaunchKernelGGL((gemmf_kernel<C>), dim3(2048), dim3(256), 0, stream, H, W2, dinv, G2, n);
    hipLaunchKernelGGL((gather_kernel<1>), dim3(ngb), dim3(256), 0, stream, rowptr, csr, G2, dinv, b2, Out, n);
}

// Round 10
// 483.398 us; speedup vs baseline: 1.3078x; 1.2814x over previous
//
#include <hip/hip_runtime.h>
#include <hip/hip_fp16.h>
#include <math.h>

#define K1 128     // input feature dim
#define C  64      // hidden == output channels
#define SCAN_B 1024
#define NPART 8    // dst-range partitions == XCD count (bid%8 round-robin)

typedef _Float16 f16x8 __attribute__((ext_vector_type(8)));
typedef _Float16 f16x4 __attribute__((ext_vector_type(4)));
typedef float    f32x4 __attribute__((ext_vector_type(4)));

// ---- edge dtype detection: int64 edges have all-zero high words ----
__global__ void detect_kernel(const int* __restrict__ e, int twoE, int* __restrict__ flag) {
    __shared__ int nz;
    if (threadIdx.x == 0) nz = 0;
    __syncthreads();
    int nchk = twoE / 2; if (nchk > 4096) nchk = 4096;
    int bad = 0;
    for (int i = threadIdx.x; i < nchk; i += blockDim.x)
        if (e[2 * i + 1] != 0) bad = 1;
    if (bad) atomicOr(&nz, 1);
    __syncthreads();
    if (threadIdx.x == 0) *flag = nz ? 0 : 1;   // 1 => int64
}

__device__ __forceinline__ int load_dst(const void* EI, int E, int e, int is64) {
    return is64 ? (int)((const long long*)EI)[(size_t)E + e] : ((const int*)EI)[(size_t)E + e];
}
__device__ __forceinline__ int load_src(const void* EI, int E, int e, int is64) {
    return is64 ? (int)((const long long*)EI)[e] : ((const int*)EI)[e];
}

// ---- per-node in-degree histogram, dst-range partitioned per XCD ----
__global__ __launch_bounds__(256) void hist_kernel(const void* __restrict__ EI, int E,
        const int* __restrict__ flag, int* __restrict__ cnt, int n) {
    const int is64 = *flag;
    const int part = blockIdx.x & (NPART - 1);
    const int span = (n + NPART - 1) / NPART;
    const int lo = part * span;
    const int hi = (lo + span < n) ? lo + span : n;
    const int blk = blockIdx.x >> 3, nblk = gridDim.x >> 3;
    for (int e = blk * 256 + threadIdx.x; e < E; e += nblk * 256) {
        int d = load_dst(EI, E, e, is64);
        if (d >= lo && d < hi) atomicAdd(&cnt[d], 1);
    }
}

// ---- exclusive scan of cnt -> rowptr (3 phases); dinv fused into phase 1 ----
__global__ __launch_bounds__(SCAN_B) void scan1_kernel(const int* __restrict__ cnt, int n,
        int* __restrict__ ex, int* __restrict__ bsum, float* __restrict__ dinv) {
    __shared__ int s[SCAN_B];
    int i = blockIdx.x * SCAN_B + threadIdx.x;
    int v = (i < n) ? cnt[i] : 0;
    s[threadIdx.x] = v;
    __syncthreads();
    for (int off = 1; off < SCAN_B; off <<= 1) {
        int t = (threadIdx.x >= off) ? s[threadIdx.x - off] : 0;
        __syncthreads();
        s[threadIdx.x] += t;
        __syncthreads();
    }
    if (i < n) {
        ex[i] = s[threadIdx.x] - v;               // exclusive within block
        dinv[i] = rsqrtf((float)(v + 1));         // +1 self-loop
    }
    if (threadIdx.x == SCAN_B - 1) bsum[blockIdx.x] = s[SCAN_B - 1];
}

__global__ void scan2_kernel(int* __restrict__ bsum, int nb) {
    const int lane = threadIdx.x & 63;
    int acc = 0;
    for (int base = 0; base < nb; base += 64) {
        int v = (base + lane < nb) ? bsum[base + lane] : 0;
        int sc = v;
        #pragma unroll
        for (int off = 1; off < 64; off <<= 1) {
            int t = __shfl_up(sc, off, 64);
            if (lane >= off) sc += t;
        }
        if (base + lane < nb) bsum[base + lane] = acc + sc - v;   // exclusive
        acc += __shfl(sc, 63, 64);
    }
}

__global__ void scan3_kernel(int* __restrict__ ex, const int* __restrict__ bsum,
                             int* __restrict__ fill, int n, int Etot) {
    for (int i = blockIdx.x * blockDim.x + threadIdx.x; i < n; i += gridDim.x * blockDim.x) {
        int v = ex[i] + bsum[i / SCAN_B];
        ex[i] = v;
        fill[i] = v;
    }
    if (blockIdx.x == 0 && threadIdx.x == 0) ex[n] = Etot;
}

// ---- scatter into CSR order, dst-range partitioned per XCD ----
__global__ __launch_bounds__(256) void scatter_kernel(const void* __restrict__ EI, int E,
        const int* __restrict__ flag, int* __restrict__ fill, int* __restrict__ csr,
        int n) {
    const int is64 = *flag;
    const int part = blockIdx.x & (NPART - 1);
    const int span = (n + NPART - 1) / NPART;
    const int lo = part * span;
    const int hi = (lo + span < n) ? lo + span : n;
    const int blk = blockIdx.x >> 3, nblk = gridDim.x >> 3;
    for (int e = blk * 256 + threadIdx.x; e < E; e += nblk * 256) {
        int d = load_dst(EI, E, e, is64);
        if (d >= lo && d < hi) {
            int s = load_src(EI, E, e, is64);
            int pos = atomicAdd(&fill[d], 1);
            csr[pos] = s;
        }
    }
}

// ---- MFMA GEMM: G = f16((X @ W) * dinv), X f32 [n x K], W f32 [K x 64].
// Per block (4 waves): one 64-row tile. X tile converted f32->f16 into LDS
// [64][K+8] (pad => even bank spread for b128 fragment reads); W staged
// TRANSPOSED Wt[n][k] once per block so B fragments are contiguous in k.
// Wave wv computes rows wv*16..wv*16+15 x all 64 cols as 4 accumulators of
// v_mfma_f32_16x16x32_f16 over K/32 k-steps. A/B packed with the SAME k-map
// (k = (lane>>4)*8 + j) -> correct for any symmetric HW layout; C/D map is
// the m89-verified col=lane&15, row=(lane>>4)*4+reg.
template<int K>
__global__ __launch_bounds__(256) void gemm_mfma(const float* __restrict__ X,
        const float* __restrict__ W, const float* __restrict__ dinv,
        __half* __restrict__ G, int n, int ntiles)
{
    __shared__ __align__(16) _Float16 Xs[64][K + 8];
    __shared__ __align__(16) _Float16 Wt[64][K + 8];
    const int lane = threadIdx.x & 63;
    const int wv = threadIdx.x >> 6;
    // stage W transposed (once; first in-loop barrier publishes it)
    for (int i = threadIdx.x; i < K * 64; i += 256) {
        int k = i >> 6, nn = i & 63;          // coalesced W read
        Wt[nn][k] = (_Float16)W[i];
    }
    _Float16* Gh = (_Float16*)G;
    for (int tile = blockIdx.x; tile < ntiles; tile += gridDim.x) {
        const int base = tile * 64;
        const int rows = (n - base < 64) ? (n - base) : 64;
        __syncthreads();                      // Xs free from prev iter readers (and Wt ready)
        for (int i = threadIdx.x; i < rows * (K / 4); i += 256) {
            const int r = i / (K / 4), c4 = i % (K / 4);
            float4 v = *(const float4*)(X + (size_t)(base + r) * K + 4 * c4);
            f16x4 h = { (_Float16)v.x, (_Float16)v.y, (_Float16)v.z, (_Float16)v.w };
            *(f16x4*)&Xs[r][4 * c4] = h;      // 8B store
        }
        __syncthreads();
        f32x4 acc0 = {0.f,0.f,0.f,0.f}, acc1 = acc0, acc2 = acc0, acc3 = acc0;
        const int m16 = lane & 15, kq = lane >> 4;
        #pragma unroll
        for (int ks = 0; ks < K / 32; ++ks) {
            f16x8 a = *(const f16x8*)&Xs[wv * 16 + m16][ks * 32 + kq * 8];
            f16x8 b0 = *(const f16x8*)&Wt[ 0 + m16][ks * 32 + kq * 8];
            f16x8 b1 = *(const f16x8*)&Wt[16 + m16][ks * 32 + kq * 8];
            f16x8 b2 = *(const f16x8*)&Wt[32 + m16][ks * 32 + kq * 8];
            f16x8 b3 = *(const f16x8*)&Wt[48 + m16][ks * 32 + kq * 8];
            acc0 = __builtin_amdgcn_mfma_f32_16x16x32_f16(a, b0, acc0, 0, 0, 0);
            acc1 = __builtin_amdgcn_mfma_f32_16x16x32_f16(a, b1, acc1, 0, 0, 0);
            acc2 = __builtin_amdgcn_mfma_f32_16x16x32_f16(a, b2, acc2, 0, 0, 0);
            acc3 = __builtin_amdgcn_mfma_f32_16x16x32_f16(a, b3, acc3, 0, 0, 0);
        }
        // D: col = lane&15 (+16c), row = (lane>>4)*4 + reg (+wv*16)
        #pragma unroll
        for (int rg = 0; rg < 4; ++rg) {
            const int r = wv * 16 + kq * 4 + rg;
            if (r < rows) {
                const float dv = dinv[base + r];
                const size_t ro = (size_t)(base + r) * C;
                Gh[ro +  0 + m16] = (_Float16)(acc0[rg] * dv);
                Gh[ro + 16 + m16] = (_Float16)(acc1[rg] * dv);
                Gh[ro + 32 + m16] = (_Float16)(acc2[rg] * dv);
                Gh[ro + 48 + m16] = (_Float16)(acc3[rg] * dv);
            }
        }
    }
}

// ---- pure CSR gather (f16 G, f32 accum), one wave per dst row ----
// MODE 0 = relu + b1 -> f32 Out ; MODE 1 = b2 + log_softmax -> f32 Out
template<int MODE>
__global__ __launch_bounds__(256) void gather_kernel(const int* __restrict__ rowptr,
        const int* __restrict__ csr, const __half* __restrict__ G,
        const float* __restrict__ dinv, const float* __restrict__ bias,
        float* __restrict__ Out, int n)
{
    const int lane = threadIdx.x & 63;
    const int v = __builtin_amdgcn_readfirstlane((int)(blockIdx.x * 4 + (threadIdx.x >> 6)));
    if (v >= n) return;
    const int start = __builtin_amdgcn_readfirstlane(rowptr[v]);
    const int end   = __builtin_amdgcn_readfirstlane(rowptr[v + 1]);
    float a[8];
    a[0] = __half2float(G[(size_t)v * C + lane]);   // self-loop term
    #pragma unroll
    for (int t = 1; t < 8; ++t) a[t] = 0.f;
    for (int base = start; base < end; base += 64) {
        int m = end - base; if (m > 64) m = 64;
        int idx = (lane < m) ? csr[base + lane] : 0;
        for (int j = 0; j < m; j += 8) {
            #pragma unroll
            for (int t = 0; t < 8; ++t) {
                if (j + t < m) {                     // wave-uniform guard
                    int s = __shfl(idx, j + t, 64);
                    a[t] += __half2float(G[(size_t)s * C + lane]);
                }
            }
        }
    }
    float acc = ((a[0] + a[1]) + (a[2] + a[3])) + ((a[4] + a[5]) + (a[6] + a[7]));
    float y = fmaf(acc, dinv[v], bias[lane]);
    if (MODE == 0) {
        Out[(size_t)v * C + lane] = y > 0.f ? y : 0.f;
    } else {
        float mx = y;
        #pragma unroll
        for (int off = 32; off > 0; off >>= 1) mx = fmaxf(mx, __shfl_xor(mx, off, 64));
        float ex = expf(y - mx);
        float l = ex;
        #pragma unroll
        for (int off = 32; off > 0; off >>= 1) l += __shfl_xor(l, off, 64);
        Out[(size_t)v * C + lane] = y - mx - logf(l);
    }
}

static inline size_t align16(size_t x) { return (x + 15) & ~(size_t)15; }

extern "C" void kernel_launch(void* const* d_in, const int* in_sizes, int n_in,
                              void* d_out, int out_size, void* d_ws, size_t ws_size,
                              hipStream_t stream)
{
    const float* X  = (const float*)d_in[0];
    const void*  EI = d_in[1];
    const float* W1 = (const float*)d_in[3];
    const float* b1 = (const float*)d_in[4];
    const float* W2 = (const float*)d_in[5];
    const float* b2 = (const float*)d_in[6];
    float* Out = (float*)d_out;

    const int n    = in_sizes[0] / K1;
    const int E    = in_sizes[1] / 2;
    const int twoE = 2 * E;
    const int nb   = (n + SCAN_B - 1) / SCAN_B;
    const int ntiles = (n + 63) / 64;

    // workspace layout (~34 MB)
    char* ws = (char*)d_ws;
    size_t off = 0;
    int*    csr    = (int*)(ws + off);    off = align16(off + (size_t)E * 4);
    int*    rowptr = (int*)(ws + off);    off = align16(off + (size_t)(n + 1) * 4);
    int*    cnt    = (int*)(ws + off);    off = align16(off + (size_t)n * 4);
    int*    bsum   = (int*)(ws + off);    off = align16(off + (size_t)(nb + 1) * 4);
    int*    flag   = (int*)(ws + off);    off = align16(off + 16);
    float*  dinv   = (float*)(ws + off);  off = align16(off + (size_t)n * 4);
    __half* G      = (__half*)(ws + off); off = align16(off + (size_t)n * C * 2);
    __half* G2     = (__half*)(ws + off); off = align16(off + (size_t)n * C * 2);
    int*    fill   = cnt;                 // cnt dead after scan1
    float*  H      = Out;                 // layer-1 activations staged in d_out (f32)

    hipLaunchKernelGGL(detect_kernel, dim3(1), dim3(256), 0, stream, (const int*)EI, twoE, flag);
    hipMemsetAsync(cnt, 0, (size_t)n * 4, stream);

    // CSR build (hist & scatter dst-partitioned, XCD-local via bid%8)
    hipLaunchKernelGGL(hist_kernel,  dim3(2048), dim3(256), 0, stream, EI, E, flag, cnt, n);
    hipLaunchKernelGGL(scan1_kernel, dim3(nb), dim3(SCAN_B), 0, stream, cnt, n, rowptr, bsum, dinv);
    hipLaunchKernelGGL(scan2_kernel, dim3(1), dim3(64), 0, stream, bsum, nb);
    hipLaunchKernelGGL(scan3_kernel, dim3(1024), dim3(256), 0, stream, rowptr, bsum, fill, n, E);
    hipLaunchKernelGGL(scatter_kernel, dim3(2048), dim3(256), 0, stream, EI, E, flag, fill, csr, n);

    const int ngb = (n + 3) / 4;   // one wave per row for gathers

    // layer 1: G = f16((X@W1)*dinv) ; H = relu(gather(G)*dinv + b1)  (H in d_out)
    hipLaunchKernelGGL((gemm_mfma<K1>), dim3(ntiles), dim3(256), 0, stream, X, W1, dinv, G, n, ntiles);
    hipLaunchKernelGGL((gather_kernel<0>), dim3(ngb), dim3(256), 0, stream, rowptr, csr, G, dinv, b1, H, n);

    // layer 2: G2 = f16((H@W2)*dinv) ; Out = log_softmax(gather(G2)*dinv + b2)
    hipLaunchKernelGGL((gemm_mfma<C>), dim3(ntiles), dim3(256), 0, stream, H, W2, dinv, G2, n, ntiles);
    hipLaunchKernelGGL((gather_kernel<1>), dim3(ngb), dim3(256), 0, stream, rowptr, csr, G2, dinv, b2, Out, n);
}